// Round 7
// baseline (3974.083 us; speedup 1.0000x reference)
//
#include <hip/hip_runtime.h>
#include <hip/hip_bf16.h>

#define L_    4096
#define DIN   512
#define DOUT  256
#define NH    4
#define HD    64

typedef unsigned short u16;
typedef __attribute__((ext_vector_type(8))) short short8;   // 8 x bf16
typedef __attribute__((ext_vector_type(4))) float floatx4;  // MFMA C/D frag

__device__ __forceinline__ float bf2f(u16 u) {
  union { unsigned u32; float f; } v; v.u32 = ((unsigned)u) << 16; return v.f;
}
__device__ __forceinline__ u16 f2bf(float f) {  // RNE
  union { float f; unsigned u; } v; v.f = f;
  unsigned r = v.u + 0x7fff + ((v.u >> 16) & 1);
  return (u16)(r >> 16);
}
__device__ __forceinline__ float lrelu_clamp(float e) {
  e = fmaxf(e, 0.2f * e);
  e = fminf(e, 30.f);
  return fmaxf(e, -80.f);
}

// ---------------------------------------------------------------------------
// MFMA layout probe (1 wave). Computes a known 16x16x32 bf16 MFMA and tests
// 4 mapping hypotheses vs an in-kernel scalar reference. Encodes the failure
// set as execution TIME (+60/+120/+240/+480 us) — readable from the rocprof
// dispatch table next round. Writes only to d_ws scratch (unchecked).
// ---------------------------------------------------------------------------
__global__ __launch_bounds__(64) void mfma_probe(float* ws_scr) {
  const int lane = threadIdx.x;
  const int q = lane >> 4, c0 = lane & 15;
  __shared__ float Af[16][32];
  __shared__ float Bf[32][16];
  for (int idx = lane; idx < 512; idx += 64) {
    int m = idx >> 5, k = idx & 31;
    Af[m][k] = (float)(((m * 7 + k * 3) % 13) - 6);     // asymmetric ints, bf16-exact
    int kk = idx >> 4, n = idx & 15;
    Bf[kk][n] = (float)(((kk * 5 + n * 11) % 9) - 4);
  }
  __syncthreads();
  union { u16 u[8]; short8 s; } A8, B8;   // fragments per ASSUMED maps
  #pragma unroll
  for (int jj = 0; jj < 8; ++jj) {
    A8.u[jj] = f2bf(Af[c0][q * 8 + jj]);        // A[m=lane&15][k=quad*8+jj]
    B8.u[jj] = f2bf(Bf[q * 8 + jj][c0]);        // B[k=quad*8+jj][n=lane&15]
  }
  floatx4 z = {0.f, 0.f, 0.f, 0.f};
  floatx4 d0 = __builtin_amdgcn_mfma_f32_16x16x32_bf16(A8.s, B8.s, z, 0, 0, 0);
  floatx4 d1 = __builtin_amdgcn_mfma_f32_16x16x32_bf16(B8.s, A8.s, z, 0, 0, 0);
  int o0 = 1, o1 = 1, o2 = 1, o3 = 1;
  #pragma unroll
  for (int r = 0; r < 4; ++r) {
    float ref = 0.f, refT = 0.f;
    for (int k = 0; k < 32; ++k) {
      ref  += Af[q * 4 + r][k] * Bf[k][c0];     // D[q*4+r][c0]   (assumed C/D map)
      refT += Af[c0][k] * Bf[k][q * 4 + r];     // D[c0][q*4+r]   (transposed C/D)
    }
    o0 &= (fabsf(d0[r] - ref)  < 0.5f);   // H0: current maps correct
    o2 &= (fabsf(d0[r] - refT) < 0.5f);   // H2: C/D transposed
    o1 &= (fabsf(d1[r] - ref)  < 0.5f);   // H1: operand order swapped
    o3 &= (fabsf(d1[r] - refT) < 0.5f);   // H3: swap + transpose
  }
  o0 = __all(o0); o1 = __all(o1); o2 = __all(o2); o3 = __all(o3);
  long iters = 0;                         // ~600 iters/us (dep-FMA ~4 cyc @2.4GHz)
  if (!o0) iters += 36000;                // +60 us
  if (!o1) iters += 72000;                // +120 us
  if (!o2) iters += 144000;               // +240 us
  if (!o3) iters += 288000;               // +480 us
  float x = ws_scr[0];
  if (!(x > -1e30f && x < 1e30f)) x = 0.f;
  for (long i = 0; i < iters; ++i) x = fmaf(x, 0.99999988f, 1.0e-9f);
  if (lane == 0)
    ws_scr[1] = x + (o0 ? 1.f : 0.f) + (o1 ? 2.f : 0.f) + (o2 ? 4.f : 0.f) + (o3 ? 8.f : 0.f);
}

// ---------------------------------------------------------------------------
// K1 scalar (verified correct in round 6; q16 removed -> faster & closer to
// fp32 ref). Stores WhJ (bf16, j-major [L][DOUT]) + s1/s2 (fp32 [NH][L]).
// ---------------------------------------------------------------------------
__global__ __launch_bounds__(256) void k1_scalar(
    const float* __restrict__ h, const float* __restrict__ W,
    const float* __restrict__ attn,
    u16* __restrict__ WhJ, float* __restrict__ s1g, float* __restrict__ s2g)
{
  const int i0 = blockIdx.x * 16;
  const int t = threadIdx.x;
  const int w = t >> 6, lane = t & 63, q = lane >> 4, c0 = lane & 15;

  float acc[4][4] = {};   // [nt][r]: rows i0+q*4+r, cols w*64+nt*16+c0
  for (int kb = 0; kb < DIN; kb += 4) {
    float4 hv[4];
    #pragma unroll
    for (int r = 0; r < 4; ++r)
      hv[r] = *(const float4*)(h + (size_t)(i0 + q * 4 + r) * DIN + kb);
    #pragma unroll
    for (int nt = 0; nt < 4; ++nt) {
      const int col = w * 64 + nt * 16 + c0;
      float4 wv = *(const float4*)(W + (size_t)col * DIN + kb);
      #pragma unroll
      for (int r = 0; r < 4; ++r)
        acc[nt][r] += hv[r].x * wv.x + hv[r].y * wv.y
                    + hv[r].z * wv.z + hv[r].w * wv.w;
    }
  }

  __shared__ float Ct[16][DOUT + 4];
  #pragma unroll
  for (int nt = 0; nt < 4; ++nt)
    #pragma unroll
    for (int r = 0; r < 4; ++r)
      Ct[q * 4 + r][w * 64 + nt * 16 + c0] = acc[nt][r];
  __syncthreads();

  if (t < 64) {  // 16 rows x 4 heads -> s1, s2 (fp32)
    const int r = t & 15, hh = t >> 4;
    float s1 = 0.f, s2 = 0.f;
    for (int d = 0; d < HD; ++d) {
      float v = Ct[r][hh * 64 + d];
      s1 += v * attn[hh * 128 + d];
      s2 += v * attn[hh * 128 + 64 + d];
    }
    s1g[hh * L_ + i0 + r] = s1;
    s2g[hh * L_ + i0 + r] = s2;
  }

  {  // WhJ store, j-major: thread t -> row r=t>>4, col-block cb=t&15 (16 bf16)
    const int r = t >> 4, cb = t & 15;
    union { u16 u[8]; int4 v; } p0, p1;
    #pragma unroll
    for (int x = 0; x < 8; ++x) p0.u[x] = f2bf(Ct[r][cb * 16 + x]);
    #pragma unroll
    for (int x = 0; x < 8; ++x) p1.u[x] = f2bf(Ct[r][cb * 16 + 8 + x]);
    u16* dst = WhJ + (size_t)(i0 + r) * DOUT + cb * 16;
    *(int4*)dst       = p0.v;
    *(int4*)(dst + 8) = p1.v;
  }
}

// ---------------------------------------------------------------------------
// K2 register-tiled VALU: i-tile 8, per-lane 8i x 8d accumulators.
// Per head: chunks of 256 j: phase E computes ex (fp32) into LDS (no dup,
// coalesced A/HBM reads); phase P does the PV outer product with coalesced
// bf16x8 WhJ loads. Fused denom, normalization (Cn bf16), projection.
// ---------------------------------------------------------------------------
__global__ __launch_bounds__(256, 2) void k2_tile(
    const int* __restrict__ A, const u16* __restrict__ WhJ,
    const float* __restrict__ s1g, const float* __restrict__ s2g,
    const float* __restrict__ out_w, const float* __restrict__ out_b,
    float* __restrict__ out)
{
  const int i0 = blockIdx.x * 8;
  const int t = threadIdx.x;
  const int w = t >> 6, lane = t & 63;
  const int dgrp = lane & 7, jsl = lane >> 3;   // PV lane: d-block, j-slice
  const int ei = t >> 5, ejb = t & 31;          // phase-E: i, j-block

  __shared__ float exT[8][260];                 // [i][j-rel], fp32
  __shared__ float dsum[8][32];
  __shared__ float redL[4][8][8][8];            // [wave][dgrp][i][dd]
  __shared__ float rcpF[8];
  __shared__ u16  CnB[8][DOUT + 8];             // Cn, bf16

  const int jrel = w * 64 + jsl * 8;            // lane's j-offset within chunk

  for (int h = 0; h < NH; ++h) {
    float acc[8][8];
    #pragma unroll
    for (int i = 0; i < 8; ++i)
      #pragma unroll
      for (int d = 0; d < 8; ++d) acc[i][d] = 0.f;
    float dreg = 0.f;
    const float s1v = s1g[h * L_ + i0 + ei];
    const float* s2h = s2g + (size_t)h * L_;
    const int* Arow = A + (size_t)(i0 + ei) * L_;

    for (int c = 0; c < 16; ++c) {
      const int jc = c * 256;
      {  // ---- phase E: ex for 8i x 256j, no duplication ----
        const int jb8 = jc + ejb * 8;
        int4   m0 = *(const int4*)(Arow + jb8);
        int4   m1 = *(const int4*)(Arow + jb8 + 4);
        float4 sa = *(const float4*)(s2h + jb8);
        float4 sb = *(const float4*)(s2h + jb8 + 4);
        const int   mk[8] = {m0.x,m0.y,m0.z,m0.w,m1.x,m1.y,m1.z,m1.w};
        const float sv[8] = {sa.x,sa.y,sa.z,sa.w,sb.x,sb.y,sb.z,sb.w};
        float ex[8];
        #pragma unroll
        for (int jj = 0; jj < 8; ++jj) {
          float x = __expf(lrelu_clamp(s1v + sv[jj]));
          ex[jj] = (mk[jj] > 0) ? x : 0.f;
          dreg += ex[jj];
        }
        *(float4*)&exT[ei][ejb * 8]     = make_float4(ex[0], ex[1], ex[2], ex[3]);
        *(float4*)&exT[ei][ejb * 8 + 4] = make_float4(ex[4], ex[5], ex[6], ex[7]);
      }
      __syncthreads();
      {  // ---- phase P: 8i x 8d x 8j outer product ----
        float ex8[8][8];
        #pragma unroll
        for (int i = 0; i < 8; ++i) {
          float4 a = *(float4*)&exT[i][jrel];
          float4 b = *(float4*)&exT[i][jrel + 4];
          ex8[i][0]=a.x; ex8[i][1]=a.y; ex8[i][2]=a.z; ex8[i][3]=a.w;
          ex8[i][4]=b.x; ex8[i][5]=b.y; ex8[i][6]=b.z; ex8[i][7]=b.w;
        }
        const u16* wp = WhJ + (size_t)(jc + jrel) * DOUT + h * 64 + dgrp * 8;
        #pragma unroll
        for (int jj = 0; jj < 8; ++jj) {
          short8 wv = *(const short8*)(wp + (size_t)jj * DOUT);
          float wf[8];
          #pragma unroll
          for (int d = 0; d < 8; ++d) wf[d] = bf2f((u16)wv[d]);
          #pragma unroll
          for (int i = 0; i < 8; ++i)
            #pragma unroll
            for (int d = 0; d < 8; ++d)
              acc[i][d] = fmaf(ex8[i][jj], wf[d], acc[i][d]);
        }
      }
      __syncthreads();  // exT consumed before next chunk overwrites
    }

    // reduce acc over j-slices (lane bits 3..5) within each wave
    #pragma unroll
    for (int i = 0; i < 8; ++i)
      #pragma unroll
      for (int d = 0; d < 8; ++d) {
        float v = acc[i][d];
        v += __shfl_xor(v, 8, 64);
        v += __shfl_xor(v, 16, 64);
        v += __shfl_xor(v, 32, 64);
        acc[i][d] = v;
      }
    if (lane < 8) {  // dgrp == lane holds its d-block
      #pragma unroll
      for (int i = 0; i < 8; ++i) {
        *(float4*)&redL[w][lane][i][0] = make_float4(acc[i][0], acc[i][1], acc[i][2], acc[i][3]);
        *(float4*)&redL[w][lane][i][4] = make_float4(acc[i][4], acc[i][5], acc[i][6], acc[i][7]);
      }
    }
    dsum[ei][ejb] = dreg;
    __syncthreads();
    if (t < 8) {
      float den = 0.f;
      for (int k = 0; k < 32; ++k) den += dsum[t][k];
      rcpF[t] = (den > 0.f) ? (1.f / den) : 0.f;   // empty row -> 0 -> out = bias
    }
    __syncthreads();
    {  // Cn = (sum over waves) * rcp, bf16
      const int ci = t >> 5, dp = t & 31;
      #pragma unroll
      for (int v = 0; v < 2; ++v) {
        const int d = dp * 2 + v;
        float s = redL[0][d >> 3][ci][d & 7] + redL[1][d >> 3][ci][d & 7]
                + redL[2][d >> 3][ci][d & 7] + redL[3][d >> 3][ci][d & 7];
        CnB[ci][h * 64 + d] = f2bf(s * rcpF[ci]);
      }
    }
    __syncthreads();
  }

  // ---- projection: out[i0+i][col] = sum_k Cn[i][k] * out_w[col][k] + b ----
  const int col = t;
  const float bias = out_b[col];
  float o[8];
  #pragma unroll
  for (int i = 0; i < 8; ++i) o[i] = bias;
  const float* wr = out_w + (size_t)col * DOUT;
  for (int k = 0; k < DOUT; k += 8) {
    float4 w0 = *(const float4*)(wr + k);
    float4 w1 = *(const float4*)(wr + k + 4);
    #pragma unroll
    for (int i = 0; i < 8; ++i) {
      short8 cv = *(const short8*)&CnB[i][k];
      o[i] += bf2f((u16)cv[0]) * w0.x + bf2f((u16)cv[1]) * w0.y
            + bf2f((u16)cv[2]) * w0.z + bf2f((u16)cv[3]) * w0.w
            + bf2f((u16)cv[4]) * w1.x + bf2f((u16)cv[5]) * w1.y
            + bf2f((u16)cv[6]) * w1.z + bf2f((u16)cv[7]) * w1.w;
    }
  }
  #pragma unroll
  for (int i = 0; i < 8; ++i)
    out[(size_t)(i0 + i) * DOUT + col] = o[i];
}

// ---------------------------------------------------------------------------
extern "C" void kernel_launch(void* const* d_in, const int* in_sizes, int n_in,
                              void* d_out, int out_size, void* d_ws, size_t ws_size,
                              hipStream_t stream) {
  const float* h     = (const float*)d_in[0];   // (4096, 512) fp32
  const int*   A     = (const int*)d_in[1];     // (4096, 4096) int32
  const float* W     = (const float*)d_in[2];   // (256, 512) fp32
  const float* attn  = (const float*)d_in[3];   // (4, 128) fp32
  const float* out_w = (const float*)d_in[4];   // (256, 256) fp32
  const float* out_b = (const float*)d_in[5];   // (256,) fp32
  float* outp = (float*)d_out;                  // (4096, 256) fp32

  // ws: WhJ bf16 [4096][256] (2 MB) | s1 f32 [4][4096] | s2 f32 [4][4096]
  u16*   WhJ = (u16*)d_ws;
  float* s1g = (float*)((char*)d_ws + (size_t)L_ * DOUT * 2);
  float* s2g = s1g + NH * L_;

  // probe first: writes 2 floats at d_ws start, then k1 overwrites them.
  hipLaunchKernelGGL(mfma_probe, dim3(1), dim3(64), 0, stream, (float*)d_ws);
  hipLaunchKernelGGL(k1_scalar, dim3(L_ / 16), dim3(256), 0, stream,
                     h, W, attn, WhJ, s1g, s2g);
  hipLaunchKernelGGL(k2_tile, dim3(L_ / 8), dim3(256), 0, stream,
                     A, WhJ, s1g, s2g, out_w, out_b, outp);
}

// Round 8
// 2065.499 us; speedup vs baseline: 1.9240x; 1.9240x over previous
//
#include <hip/hip_runtime.h>
#include <hip/hip_bf16.h>

#define L_    4096
#define DIN   512
#define DOUT  256
#define NH    4
#define HD    64

typedef unsigned short u16;
typedef __attribute__((ext_vector_type(8))) short short8;   // 8 x bf16
typedef __attribute__((ext_vector_type(4))) float floatx4;  // MFMA C/D frag

__device__ __forceinline__ float bf2f(u16 u) {
  union { unsigned u32; float f; } v; v.u32 = ((unsigned)u) << 16; return v.f;
}
__device__ __forceinline__ u16 f2bf(float f) {  // RNE
  union { float f; unsigned u; } v; v.f = f;
  unsigned r = v.u + 0x7fff + ((v.u >> 16) & 1);
  return (u16)(r >> 16);
}
__device__ __forceinline__ float lrelu_clamp(float e) {
  e = fmaxf(e, 0.2f * e);
  e = fminf(e, 30.f);
  return fmaxf(e, -80.f);
}

// ---------------------------------------------------------------------------
// Layout probe, SELF-CALIBRATING encoding: dur = code * 85000 iters
// (~code * 0.6 ms at the 6.7-7.2 ns/iter measured for this exact loop in r7).
//   code 1: D[q*4+r][c0]   (H0: guide map — row=quad*4+reg, col=lane&15)
//   code 2: D[r*4+q][c0]   (reg/quad swapped)
//   code 3: D[c0][q*4+r]   (transposed)
//   code 4: D[c0][r*4+q]   (transposed + swapped)
//   code 5: none match     (A/B slot k-maps differ; cancellation broken)
// Exact small-int matrices; all hypotheses pairwise distinguishable.
// ---------------------------------------------------------------------------
__global__ __launch_bounds__(64) void layout_probe(float* scr, long unit) {
  const int lane = threadIdx.x;
  const int q = lane >> 4, c0 = lane & 15;
  __shared__ float Af[16][32];
  __shared__ float Bf[32][16];
  for (int idx = lane; idx < 512; idx += 64) {
    int m = idx >> 5, k = idx & 31;
    Af[m][k] = (float)(((m * 7 + k * 3) % 13) - 6);   // rows pairwise distinct
    int kk = idx >> 4, n = idx & 15;
    Bf[kk][n] = (float)(((kk * 5 + n * 11) % 9) - 4);
  }
  __syncthreads();
  union { u16 u[8]; short8 s; } A8, B8;   // fill per ASSUMED A/B maps
  #pragma unroll
  for (int jj = 0; jj < 8; ++jj) {
    A8.u[jj] = f2bf(Af[c0][q * 8 + jj]);        // A[m=lane&15][k=quad*8+jj]
    B8.u[jj] = f2bf(Bf[q * 8 + jj][c0]);        // B[k=quad*8+jj][n=lane&15]
  }
  floatx4 z = {0.f, 0.f, 0.f, 0.f};
  floatx4 d0 = __builtin_amdgcn_mfma_f32_16x16x32_bf16(A8.s, B8.s, z, 0, 0, 0);
  int c1 = 1, c2 = 1, c3 = 1, c4 = 1;
  #pragma unroll
  for (int r = 0; r < 4; ++r) {
    float e1 = 0.f, e2 = 0.f, e3 = 0.f, e4 = 0.f;
    for (int k = 0; k < 32; ++k) {
      e1 += Af[q * 4 + r][k] * Bf[k][c0];
      e2 += Af[r * 4 + q][k] * Bf[k][c0];
      e3 += Af[c0][k] * Bf[k][q * 4 + r];
      e4 += Af[c0][k] * Bf[k][r * 4 + q];
    }
    c1 &= (fabsf(d0[r] - e1) < 0.5f);
    c2 &= (fabsf(d0[r] - e2) < 0.5f);
    c3 &= (fabsf(d0[r] - e3) < 0.5f);
    c4 &= (fabsf(d0[r] - e4) < 0.5f);
  }
  c1 = __all(c1); c2 = __all(c2); c3 = __all(c3); c4 = __all(c4);
  int code = c1 ? 1 : (c2 ? 2 : (c3 ? 3 : (c4 ? 4 : 5)));
  long iters = (long)code * unit;
  float x = scr[0];
  if (!(x > -1e30f && x < 1e30f)) x = 0.f;
  for (long i = 0; i < iters; ++i) x = fmaf(x, 0.99999988f, 1.0e-9f);
  if (lane == 0) scr[1] = x + (float)code;
}

// ---------------------------------------------------------------------------
// K1 scalar (verified round 6/7). WhJ (bf16, j-major [L][DOUT]) + s1/s2 fp32.
// ---------------------------------------------------------------------------
__global__ __launch_bounds__(256) void k1_scalar(
    const float* __restrict__ h, const float* __restrict__ W,
    const float* __restrict__ attn,
    u16* __restrict__ WhJ, float* __restrict__ s1g, float* __restrict__ s2g)
{
  const int i0 = blockIdx.x * 16;
  const int t = threadIdx.x;
  const int w = t >> 6, lane = t & 63, q = lane >> 4, c0 = lane & 15;

  float acc[4][4] = {};   // [nt][r]: rows i0+q*4+r, cols w*64+nt*16+c0
  for (int kb = 0; kb < DIN; kb += 4) {
    float4 hv[4];
    #pragma unroll
    for (int r = 0; r < 4; ++r)
      hv[r] = *(const float4*)(h + (size_t)(i0 + q * 4 + r) * DIN + kb);
    #pragma unroll
    for (int nt = 0; nt < 4; ++nt) {
      const int col = w * 64 + nt * 16 + c0;
      float4 wv = *(const float4*)(W + (size_t)col * DIN + kb);
      #pragma unroll
      for (int r = 0; r < 4; ++r)
        acc[nt][r] += hv[r].x * wv.x + hv[r].y * wv.y
                    + hv[r].z * wv.z + hv[r].w * wv.w;
    }
  }

  __shared__ float Ct[16][DOUT + 4];
  #pragma unroll
  for (int nt = 0; nt < 4; ++nt)
    #pragma unroll
    for (int r = 0; r < 4; ++r)
      Ct[q * 4 + r][w * 64 + nt * 16 + c0] = acc[nt][r];
  __syncthreads();

  if (t < 64) {  // 16 rows x 4 heads -> s1, s2 (fp32)
    const int r = t & 15, hh = t >> 4;
    float s1 = 0.f, s2 = 0.f;
    for (int d = 0; d < HD; ++d) {
      float v = Ct[r][hh * 64 + d];
      s1 += v * attn[hh * 128 + d];
      s2 += v * attn[hh * 128 + 64 + d];
    }
    s1g[hh * L_ + i0 + r] = s1;
    s2g[hh * L_ + i0 + r] = s2;
  }

  {  // WhJ store, j-major: thread t -> row r=t>>4, col-block cb=t&15
    const int r = t >> 4, cb = t & 15;
    union { u16 u[8]; int4 v; } p0, p1;
    #pragma unroll
    for (int x = 0; x < 8; ++x) p0.u[x] = f2bf(Ct[r][cb * 16 + x]);
    #pragma unroll
    for (int x = 0; x < 8; ++x) p1.u[x] = f2bf(Ct[r][cb * 16 + 8 + x]);
    u16* dst = WhJ + (size_t)(i0 + r) * DOUT + cb * 16;
    *(int4*)dst       = p0.v;
    *(int4*)(dst + 8) = p1.v;
  }
}

// ---------------------------------------------------------------------------
// K2 register-tiled VALU (verified round 7). i-tile 8, 8i x 8d acc/lane.
// ---------------------------------------------------------------------------
__global__ __launch_bounds__(256, 2) void k2_tile(
    const int* __restrict__ A, const u16* __restrict__ WhJ,
    const float* __restrict__ s1g, const float* __restrict__ s2g,
    const float* __restrict__ out_w, const float* __restrict__ out_b,
    float* __restrict__ out)
{
  const int i0 = blockIdx.x * 8;
  const int t = threadIdx.x;
  const int w = t >> 6, lane = t & 63;
  const int dgrp = lane & 7, jsl = lane >> 3;
  const int ei = t >> 5, ejb = t & 31;

  __shared__ float exT[8][260];
  __shared__ float dsum[8][32];
  __shared__ float redL[4][8][8][8];
  __shared__ float rcpF[8];
  __shared__ u16  CnB[8][DOUT + 8];

  const int jrel = w * 64 + jsl * 8;

  for (int h = 0; h < NH; ++h) {
    float acc[8][8];
    #pragma unroll
    for (int i = 0; i < 8; ++i)
      #pragma unroll
      for (int d = 0; d < 8; ++d) acc[i][d] = 0.f;
    float dreg = 0.f;
    const float s1v = s1g[h * L_ + i0 + ei];
    const float* s2h = s2g + (size_t)h * L_;
    const int* Arow = A + (size_t)(i0 + ei) * L_;

    for (int c = 0; c < 16; ++c) {
      const int jc = c * 256;
      {  // ---- phase E ----
        const int jb8 = jc + ejb * 8;
        int4   m0 = *(const int4*)(Arow + jb8);
        int4   m1 = *(const int4*)(Arow + jb8 + 4);
        float4 sa = *(const float4*)(s2h + jb8);
        float4 sb = *(const float4*)(s2h + jb8 + 4);
        const int   mk[8] = {m0.x,m0.y,m0.z,m0.w,m1.x,m1.y,m1.z,m1.w};
        const float sv[8] = {sa.x,sa.y,sa.z,sa.w,sb.x,sb.y,sb.z,sb.w};
        float ex[8];
        #pragma unroll
        for (int jj = 0; jj < 8; ++jj) {
          float x = __expf(lrelu_clamp(s1v + sv[jj]));
          ex[jj] = (mk[jj] > 0) ? x : 0.f;
          dreg += ex[jj];
        }
        *(float4*)&exT[ei][ejb * 8]     = make_float4(ex[0], ex[1], ex[2], ex[3]);
        *(float4*)&exT[ei][ejb * 8 + 4] = make_float4(ex[4], ex[5], ex[6], ex[7]);
      }
      __syncthreads();
      {  // ---- phase P ----
        float ex8[8][8];
        #pragma unroll
        for (int i = 0; i < 8; ++i) {
          float4 a = *(float4*)&exT[i][jrel];
          float4 b = *(float4*)&exT[i][jrel + 4];
          ex8[i][0]=a.x; ex8[i][1]=a.y; ex8[i][2]=a.z; ex8[i][3]=a.w;
          ex8[i][4]=b.x; ex8[i][5]=b.y; ex8[i][6]=b.z; ex8[i][7]=b.w;
        }
        const u16* wp = WhJ + (size_t)(jc + jrel) * DOUT + h * 64 + dgrp * 8;
        #pragma unroll
        for (int jj = 0; jj < 8; ++jj) {
          short8 wv = *(const short8*)(wp + (size_t)jj * DOUT);
          float wf[8];
          #pragma unroll
          for (int d = 0; d < 8; ++d) wf[d] = bf2f((u16)wv[d]);
          #pragma unroll
          for (int i = 0; i < 8; ++i)
            #pragma unroll
            for (int d = 0; d < 8; ++d)
              acc[i][d] = fmaf(ex8[i][jj], wf[d], acc[i][d]);
        }
      }
      __syncthreads();
    }

    #pragma unroll
    for (int i = 0; i < 8; ++i)
      #pragma unroll
      for (int d = 0; d < 8; ++d) {
        float v = acc[i][d];
        v += __shfl_xor(v, 8, 64);
        v += __shfl_xor(v, 16, 64);
        v += __shfl_xor(v, 32, 64);
        acc[i][d] = v;
      }
    if (lane < 8) {
      #pragma unroll
      for (int i = 0; i < 8; ++i) {
        *(float4*)&redL[w][lane][i][0] = make_float4(acc[i][0], acc[i][1], acc[i][2], acc[i][3]);
        *(float4*)&redL[w][lane][i][4] = make_float4(acc[i][4], acc[i][5], acc[i][6], acc[i][7]);
      }
    }
    dsum[ei][ejb] = dreg;
    __syncthreads();
    if (t < 8) {
      float den = 0.f;
      for (int k = 0; k < 32; ++k) den += dsum[t][k];
      rcpF[t] = (den > 0.f) ? (1.f / den) : 0.f;
    }
    __syncthreads();
    {
      const int ci = t >> 5, dp = t & 31;
      #pragma unroll
      for (int v = 0; v < 2; ++v) {
        const int d = dp * 2 + v;
        float s = redL[0][d >> 3][ci][d & 7] + redL[1][d >> 3][ci][d & 7]
                + redL[2][d >> 3][ci][d & 7] + redL[3][d >> 3][ci][d & 7];
        CnB[ci][h * 64 + d] = f2bf(s * rcpF[ci]);
      }
    }
    __syncthreads();
  }

  const int col = t;
  const float bias = out_b[col];
  float o[8];
  #pragma unroll
  for (int i = 0; i < 8; ++i) o[i] = bias;
  const float* wr = out_w + (size_t)col * DOUT;
  for (int k = 0; k < DOUT; k += 8) {
    float4 w0 = *(const float4*)(wr + k);
    float4 w1 = *(const float4*)(wr + k + 4);
    #pragma unroll
    for (int i = 0; i < 8; ++i) {
      short8 cv = *(const short8*)&CnB[i][k];
      o[i] += bf2f((u16)cv[0]) * w0.x + bf2f((u16)cv[1]) * w0.y
            + bf2f((u16)cv[2]) * w0.z + bf2f((u16)cv[3]) * w0.w
            + bf2f((u16)cv[4]) * w1.x + bf2f((u16)cv[5]) * w1.y
            + bf2f((u16)cv[6]) * w1.z + bf2f((u16)cv[7]) * w1.w;
    }
  }
  #pragma unroll
  for (int i = 0; i < 8; ++i)
    out[(size_t)(i0 + i) * DOUT + col] = o[i];
}

// ---------------------------------------------------------------------------
extern "C" void kernel_launch(void* const* d_in, const int* in_sizes, int n_in,
                              void* d_out, int out_size, void* d_ws, size_t ws_size,
                              hipStream_t stream) {
  const float* h     = (const float*)d_in[0];   // (4096, 512) fp32
  const int*   A     = (const int*)d_in[1];     // (4096, 4096) int32
  const float* W     = (const float*)d_in[2];   // (256, 512) fp32
  const float* attn  = (const float*)d_in[3];   // (4, 128) fp32
  const float* out_w = (const float*)d_in[4];   // (256, 256) fp32
  const float* out_b = (const float*)d_in[5];   // (256,) fp32
  float* outp = (float*)d_out;                  // (4096, 256) fp32

  // ws: WhJ bf16 [4096][256] (2 MB) | s1 f32 [4][4096] | s2 f32 [4][4096]
  u16*   WhJ = (u16*)d_ws;
  float* s1g = (float*)((char*)d_ws + (size_t)L_ * DOUT * 2);
  float* s2g = s1g + NH * L_;

  // probe first (writes 8 B at ws start; k1 then overwrites). dur = code*~600us.
  hipLaunchKernelGGL(layout_probe, dim3(1), dim3(64), 0, stream,
                     (float*)d_ws, (long)85000);
  hipLaunchKernelGGL(k1_scalar, dim3(L_ / 16), dim3(256), 0, stream,
                     h, W, attn, WhJ, s1g, s2g);
  hipLaunchKernelGGL(k2_tile, dim3(L_ / 8), dim3(256), 0, stream,
                     A, WhJ, s1g, s2g, out_w, out_b, outp);
}

// Round 10
// 309.553 us; speedup vs baseline: 12.8381x; 6.6725x over previous
//
#include <hip/hip_runtime.h>
#include <hip/hip_bf16.h>

#define L_    4096
#define DIN   512
#define DOUT  256
#define NH    4
#define HD    64

typedef unsigned short u16;
typedef __attribute__((ext_vector_type(8))) short short8;   // 8 x bf16
typedef __attribute__((ext_vector_type(4))) float floatx4;  // MFMA C/D frag

__device__ __forceinline__ float bf2f(u16 u) {
  union { unsigned u32; float f; } v; v.u32 = ((unsigned)u) << 16; return v.f;
}
__device__ __forceinline__ u16 f2bf(float f) {  // RNE
  union { float f; unsigned u; } v; v.f = f;
  unsigned r = v.u + 0x7fff + ((v.u >> 16) & 1);
  return (u16)(r >> 16);
}
__device__ __forceinline__ short8 pack8(const float* __restrict__ p) {
  float4 a = *(const float4*)p, b = *(const float4*)(p + 4);
  union { u16 u[8]; short8 s; } r;
  r.u[0] = f2bf(a.x); r.u[1] = f2bf(a.y); r.u[2] = f2bf(a.z); r.u[3] = f2bf(a.w);
  r.u[4] = f2bf(b.x); r.u[5] = f2bf(b.y); r.u[6] = f2bf(b.z); r.u[7] = f2bf(b.w);
  return r.s;
}
__device__ __forceinline__ float lrelu_clamp(float e) {
  e = fmaxf(e, 0.2f * e);
  e = fminf(e, 30.f);
  return fmaxf(e, -80.f);
}

// ---------------------------------------------------------------------------
// In-kernel MFMA self-calibration.
// Fill convention (mine): A-slot jj of lane l holds A[l&15][(l>>4)*8+jj],
//                         B-slot jj of lane l holds B[(l>>4)*8+jj][l&15].
// Probe1/2 (constant-per-lane fills, layout-map-free) discover the C/D map:
// reg r of lane l holds D[rowm[r]][colm[r]]. Probe3 verifies the whole
// fill->mfma->readout contract on a known asymmetric integer tile at the
// discovered positions (catches A/B k-pairing mismatch too).
// All probe arithmetic exact in bf16/fp32. Returns wave-uniform ok.
// ---------------------------------------------------------------------------
__device__ __forceinline__ int mfma_selfcal(int lane, int* rowm, int* colm) {
  const int q = lane >> 4, c0 = lane & 15;
  union { u16 u[8]; short8 s; } a1, b1, a2, b2, ta, tb;
  const u16 one = f2bf(1.f);
  const u16 cid = f2bf((float)c0);
  #pragma unroll
  for (int j = 0; j < 8; ++j) {
    a1.u[j] = cid; b1.u[j] = one;       // D1 = 32*row
    a2.u[j] = one; b2.u[j] = cid;       // D2 = 32*col
    const int k = q * 8 + j;
    ta.u[j] = f2bf((float)(((c0 * 7 + k * 3) % 13) - 6));   // A[c0][k]
    tb.u[j] = f2bf((float)(((k * 5 + c0 * 11) % 9) - 4));   // B[k][c0]
  }
  floatx4 z = {0.f, 0.f, 0.f, 0.f};
  floatx4 dr = __builtin_amdgcn_mfma_f32_16x16x32_bf16(a1.s, b1.s, z, 0, 0, 0);
  floatx4 dc = __builtin_amdgcn_mfma_f32_16x16x32_bf16(a2.s, b2.s, z, 0, 0, 0);
  floatx4 dt = __builtin_amdgcn_mfma_f32_16x16x32_bf16(ta.s, tb.s, z, 0, 0, 0);
  int ok = 1;
  #pragma unroll
  for (int r = 0; r < 4; ++r) {
    int ri = (int)(dr[r] * 0.03125f + 0.5f);
    int ci = (int)(dc[r] * 0.03125f + 0.5f);
    ok &= (fabsf(dr[r] - 32.f * (float)ri) < 0.25f) && (ri >= 0) && (ri < 16);
    ok &= (fabsf(dc[r] - 32.f * (float)ci) < 0.25f) && (ci >= 0) && (ci < 16);
    rowm[r] = ri; colm[r] = ci;
    float ref = 0.f;
    for (int k = 0; k < 32; ++k)
      ref += (float)(((ri * 7 + k * 3) % 13) - 6)
           * (float)(((k * 5 + ci * 11) % 9) - 4);
    ok &= (fabsf(dt[r] - ref) < 0.5f);
  }
  return __all(ok) ? 1 : 0;
}

// ---------------------------------------------------------------------------
// K1: Wh = h @ W.T. MFMA path (self-calibrated C/D scatter) or scalar
// fallback (r6-verified). Shared epilogue: s1/s2 fp32 + WhT bf16 d-major.
// ---------------------------------------------------------------------------
__global__ __launch_bounds__(256) void k1_wh(
    const float* __restrict__ h, const float* __restrict__ W,
    const float* __restrict__ attn,
    u16* __restrict__ WhT, float* __restrict__ s1g, float* __restrict__ s2g)
{
  const int i0 = blockIdx.x * 16;
  const int t = threadIdx.x;
  const int w = t >> 6, lane = t & 63, q = lane >> 4, c0 = lane & 15;
  int rowm[4], colm[4];
  const int ok = mfma_selfcal(lane, rowm, colm);

  __shared__ float Ct[16][DOUT + 4];

  if (ok) {  // ---- MFMA path ----
    floatx4 acc[4] = {};
    const float* hrow = h + (size_t)(i0 + c0) * DIN;   // A[m=c0][k]
    #pragma unroll 2
    for (int kt = 0; kt < DIN / 32; ++kt) {
      const int kb = kt * 32 + q * 8;
      short8 af = pack8(hrow + kb);
      #pragma unroll
      for (int nt = 0; nt < 4; ++nt) {
        const int col = w * 64 + nt * 16 + c0;         // B[k][n=c0]
        short8 bf = pack8(W + (size_t)col * DIN + kb);
        acc[nt] = __builtin_amdgcn_mfma_f32_16x16x32_bf16(af, bf, acc[nt], 0, 0, 0);
      }
    }
    #pragma unroll
    for (int nt = 0; nt < 4; ++nt)
      #pragma unroll
      for (int r = 0; r < 4; ++r)
        Ct[rowm[r]][w * 64 + nt * 16 + colm[r]] = acc[nt][r];
  } else {   // ---- scalar fallback (r6-verified) ----
    float acc[4][4] = {};
    for (int kb = 0; kb < DIN; kb += 4) {
      float4 hv[4];
      #pragma unroll
      for (int r = 0; r < 4; ++r)
        hv[r] = *(const float4*)(h + (size_t)(i0 + q * 4 + r) * DIN + kb);
      #pragma unroll
      for (int nt = 0; nt < 4; ++nt) {
        const int col = w * 64 + nt * 16 + c0;
        float4 wv = *(const float4*)(W + (size_t)col * DIN + kb);
        #pragma unroll
        for (int r = 0; r < 4; ++r)
          acc[nt][r] += hv[r].x * wv.x + hv[r].y * wv.y
                      + hv[r].z * wv.z + hv[r].w * wv.w;
      }
    }
    #pragma unroll
    for (int nt = 0; nt < 4; ++nt)
      #pragma unroll
      for (int r = 0; r < 4; ++r)
        Ct[q * 4 + r][w * 64 + nt * 16 + c0] = acc[nt][r];
  }
  __syncthreads();

  if (t < 64) {  // 16 rows x 4 heads -> s1, s2 (fp32)
    const int r = t & 15, hh = t >> 4;
    float s1 = 0.f, s2 = 0.f;
    for (int d = 0; d < HD; ++d) {
      float v = Ct[r][hh * 64 + d];
      s1 += v * attn[hh * 128 + d];
      s2 += v * attn[hh * 128 + 64 + d];
    }
    s1g[hh * L_ + i0 + r] = s1;
    s2g[hh * L_ + i0 + r] = s2;
  }

  {  // WhT store (d-major [DOUT][L]): thread t = column c
    const int c = t;
    union { u16 u[8]; int4 v; } p0, p1;
    #pragma unroll
    for (int r = 0; r < 8; ++r) p0.u[r] = f2bf(Ct[r][c]);
    #pragma unroll
    for (int r = 0; r < 8; ++r) p1.u[r] = f2bf(Ct[r + 8][c]);
    *(int4*)(WhT + (size_t)c * L_ + i0)     = p0.v;
    *(int4*)(WhT + (size_t)c * L_ + i0 + 8) = p1.v;
  }
}

// ---------------------------------------------------------------------------
// K2: masked softmax + PV + fused out_w projection. MFMA path uses the
// self-calibrated map (rcp via dynamic shuffle, scatter stores); fallback is
// the r6-verified per-row scalar pipeline (16 rows sequentially).
// ---------------------------------------------------------------------------
__global__ __launch_bounds__(256) void k2_attn(
    const int* __restrict__ A, const u16* __restrict__ WhT,
    const float* __restrict__ s1g, const float* __restrict__ s2g,
    const float* __restrict__ out_w, const float* __restrict__ out_b,
    float* __restrict__ out)
{
  const int i0 = blockIdx.x * 16;
  const int t = threadIdx.x;
  const int w = t >> 6, lane = t & 63, q = lane >> 4, c0 = lane & 15;
  int rowm[4], colm[4];
  const int ok = mfma_selfcal(lane, rowm, colm);

  __shared__ u16 CnL[16][DOUT + 8];

  if (ok) {  // ---- MFMA path ----
    const float s1v = s1g[w * L_ + i0 + c0];
    const int* Arow = A + (size_t)(i0 + c0) * L_;
    const float* s2h = s2g + (size_t)w * L_;
    const u16* WhTh = WhT + (size_t)(w * 64 + c0) * L_;

    floatx4 acc[4] = {};
    float dpart = 0.f;
    #pragma unroll 2
    for (int kt = 0; kt < L_ / 32; ++kt) {
      const int kb = kt * 32 + q * 8;
      int4   m0 = *(const int4*)(Arow + kb);
      int4   m1 = *(const int4*)(Arow + kb + 4);
      float4 sa = *(const float4*)(s2h + kb);
      float4 sb = *(const float4*)(s2h + kb + 4);
      const int   mk[8] = {m0.x, m0.y, m0.z, m0.w, m1.x, m1.y, m1.z, m1.w};
      const float sv[8] = {sa.x, sa.y, sa.z, sa.w, sb.x, sb.y, sb.z, sb.w};
      union { u16 u[8]; short8 s; } pf;             // P A-frag: my row = c0
      #pragma unroll
      for (int jj = 0; jj < 8; ++jj) {
        float ex = __expf(lrelu_clamp(s1v + sv[jj]));
        ex = (mk[jj] > 0) ? ex : 0.f;               // mask = (A > 0)
        dpart += ex;
        pf.u[jj] = f2bf(ex);
      }
      #pragma unroll
      for (int nt = 0; nt < 4; ++nt) {
        short8 bfr = *(const short8*)(WhTh + (size_t)(nt * 16) * L_ + kb);
        acc[nt] = __builtin_amdgcn_mfma_f32_16x16x32_bf16(pf.s, bfr, acc[nt], 0, 0, 0);
      }
    }
    // denom of my row c0 (sum of MY ex values across the 4 q-groups)
    dpart += __shfl_xor(dpart, 16, 64);
    dpart += __shfl_xor(dpart, 32, 64);
    const float rcp = (dpart > 0.f) ? (1.f / dpart) : 0.f;

    // normalize + store Cn (bf16) through discovered map; rcp of row rowm[r]
    // lives in lane rowm[r] (its c0 == rowm[r]) -> dynamic shuffle.
    #pragma unroll
    for (int nt = 0; nt < 4; ++nt)
      #pragma unroll
      for (int r = 0; r < 4; ++r) {
        float rs = __shfl(rcp, rowm[r], 64);
        CnL[rowm[r]][w * 64 + nt * 16 + colm[r]] = f2bf(acc[nt][r] * rs);
      }
    __syncthreads();

    // projection: Out2(16x256) = Cn @ out_w.T; wave w -> cols [64w, 64w+64)
    floatx4 o[4] = {};
    #pragma unroll
    for (int kt = 0; kt < DOUT / 32; ++kt) {
      const int kb = kt * 32 + q * 8;
      short8 afr = *(const short8*)(&CnL[c0][kb]);  // A[m=c0][k]
      #pragma unroll
      for (int nt = 0; nt < 4; ++nt) {
        const int col = w * 64 + nt * 16 + c0;      // B[k][n=c0]
        short8 bfo = pack8(out_w + (size_t)col * DOUT + kb);
        o[nt] = __builtin_amdgcn_mfma_f32_16x16x32_bf16(afr, bfo, o[nt], 0, 0, 0);
      }
    }
    #pragma unroll
    for (int nt = 0; nt < 4; ++nt)
      #pragma unroll
      for (int r = 0; r < 4; ++r) {
        const int col = w * 64 + nt * 16 + colm[r];
        out[(size_t)(i0 + rowm[r]) * DOUT + col] = o[nt][r] + out_b[col];
      }
  } else {   // ---- scalar fallback (r6-verified), 16 rows sequentially ----
    __shared__ float exL[L_];
    __shared__ float red[256];
    __shared__ float Cn1[DOUT];
    __shared__ float rcpS;
    for (int ir = 0; ir < 16; ++ir) {
      const int i = i0 + ir;
      const int* Arow = A + (size_t)i * L_;
      for (int hh = 0; hh < NH; ++hh) {
        const float s1v = s1g[hh * L_ + i];
        const float* s2h = s2g + (size_t)hh * L_;
        float part = 0.f;
        for (int j = t; j < L_; j += 256) {
          float e = s1v + s2h[j];
          e = fmaxf(e, 0.2f * e);
          float ex = (Arow[j] > 0) ? __expf(e) : 0.f;
          exL[j] = ex;
          part += ex;
        }
        red[t] = part;
        __syncthreads();
        for (int s = 128; s > 0; s >>= 1) {
          if (t < s) red[t] += red[t + s];
          __syncthreads();
        }
        if (t == 0) rcpS = (red[0] > 0.f) ? (1.f / red[0]) : 0.f;
        __syncthreads();
        const float rcp = rcpS;
        const int d = t & 63, sl = t >> 6;
        const u16* wrow = WhT + (size_t)(hh * HD + d) * L_;
        float a = 0.f;
        for (int j = sl * 1024; j < sl * 1024 + 1024; ++j)
          a += exL[j] * bf2f(wrow[j]);
        __syncthreads();
        red[t] = a;
        __syncthreads();
        if (t < 64)
          Cn1[hh * HD + t] = (red[t] + red[64 + t] + red[128 + t] + red[192 + t]) * rcp;
        __syncthreads();
      }
      {
        const int c = t;
        const float* wr = out_w + (size_t)c * DOUT;
        float o = out_b[c];
        for (int k = 0; k < DOUT; ++k) o += Cn1[k] * wr[k];
        out[(size_t)i * DOUT + c] = o;
      }
      __syncthreads();
    }
  }
}

// ---------------------------------------------------------------------------
extern "C" void kernel_launch(void* const* d_in, const int* in_sizes, int n_in,
                              void* d_out, int out_size, void* d_ws, size_t ws_size,
                              hipStream_t stream) {
  const float* h     = (const float*)d_in[0];   // (4096, 512) fp32
  const int*   A     = (const int*)d_in[1];     // (4096, 4096) int32
  const float* W     = (const float*)d_in[2];   // (256, 512) fp32
  const float* attn  = (const float*)d_in[3];   // (4, 128) fp32
  const float* out_w = (const float*)d_in[4];   // (256, 256) fp32
  const float* out_b = (const float*)d_in[5];   // (256,) fp32
  float* outp = (float*)d_out;                  // (4096, 256) fp32

  // ws: WhT bf16 [256][4096] (2 MB) | s1 f32 [4][4096] | s2 f32 [4][4096]
  u16*   WhT = (u16*)d_ws;
  float* s1g = (float*)((char*)d_ws + (size_t)DOUT * L_ * 2);
  float* s2g = s1g + NH * L_;

  hipLaunchKernelGGL(k1_wh, dim3(L_ / 16), dim3(256), 0, stream,
                     h, W, attn, WhT, s1g, s2g);
  hipLaunchKernelGGL(k2_attn, dim3(L_ / 16), dim3(256), 0, stream,
                     A, WhT, s1g, s2g, out_w, out_b, outp);
}

// Round 11
// 219.675 us; speedup vs baseline: 18.0907x; 1.4091x over previous
//
#include <hip/hip_runtime.h>
#include <hip/hip_bf16.h>

#define L_    4096
#define DIN   512
#define DOUT  256
#define NH    4
#define HD    64

typedef unsigned short u16;
typedef __attribute__((ext_vector_type(8))) short short8;   // 8 x bf16
typedef __attribute__((ext_vector_type(4))) float floatx4;  // MFMA C/D frag

__device__ __forceinline__ float bf2f(u16 u) {
  union { unsigned u32; float f; } v; v.u32 = ((unsigned)u) << 16; return v.f;
}
__device__ __forceinline__ u16 f2bf(float f) {  // RNE
  union { float f; unsigned u; } v; v.f = f;
  unsigned r = v.u + 0x7fff + ((v.u >> 16) & 1);
  return (u16)(r >> 16);
}
// HW packed fp32x2 -> bf16x2 (RNE)
__device__ __forceinline__ unsigned cvt2(float a, float b) {
  __hip_bfloat162 v = __float22bfloat162_rn(make_float2(a, b));
  return *reinterpret_cast<unsigned*>(&v);
}
__device__ __forceinline__ short8 pack8(const float* __restrict__ p) {
  float4 a = *(const float4*)p, b = *(const float4*)(p + 4);
  union { unsigned u[4]; short8 s; } r;
  r.u[0] = cvt2(a.x, a.y); r.u[1] = cvt2(a.z, a.w);
  r.u[2] = cvt2(b.x, b.y); r.u[3] = cvt2(b.z, b.w);
  return r.s;
}
__device__ __forceinline__ float lrelu_clamp(float e) {
  e = fmaxf(e, 0.2f * e);
  e = fminf(e, 30.f);
  return fmaxf(e, -80.f);
}

// ---------------------------------------------------------------------------
// C/D map discovery (r10-verified contract). Layout-map-free probes:
//   A=row-id,B=1 -> D=32*row ; A=1,B=col-id -> D=32*col.
// Fill convention: A-slot jj of lane l = A[l&15][(l>>4)*8+jj],
//                  B-slot jj of lane l = B[(l>>4)*8+jj][l&15].
// ---------------------------------------------------------------------------
__device__ __forceinline__ void mfma_cdmap(int lane, int* rowm, int* colm) {
  const int c0 = lane & 15;
  union { u16 u[8]; short8 s; } a1, b1, a2, b2;
  const u16 one = f2bf(1.f), cid = f2bf((float)c0);
  #pragma unroll
  for (int j = 0; j < 8; ++j) { a1.u[j] = cid; b1.u[j] = one; a2.u[j] = one; b2.u[j] = cid; }
  floatx4 z = {0.f, 0.f, 0.f, 0.f};
  floatx4 dr = __builtin_amdgcn_mfma_f32_16x16x32_bf16(a1.s, b1.s, z, 0, 0, 0);
  floatx4 dc = __builtin_amdgcn_mfma_f32_16x16x32_bf16(a2.s, b2.s, z, 0, 0, 0);
  #pragma unroll
  for (int r = 0; r < 4; ++r) {
    rowm[r] = (int)(dr[r] * 0.03125f + 0.5f);
    colm[r] = (int)(dc[r] * 0.03125f + 0.5f);
  }
}

// ---------------------------------------------------------------------------
// K1: Wh = h @ W.T. Block 1024 = 16 waves: wave (cg = wv&3 -> cols cg*64..+63,
// kc = wv>>2 -> K-chunk kc*128..+127). Phased 2-plane LDS reduction over kc.
// Epilogue: s1/s2 fp32 + WhT bf16 d-major [DOUT][L].
// ---------------------------------------------------------------------------
__global__ __launch_bounds__(1024) void k1_wh(
    const float* __restrict__ h, const float* __restrict__ W,
    const float* __restrict__ attn,
    u16* __restrict__ WhT, float* __restrict__ s1g, float* __restrict__ s2g)
{
  const int i0 = blockIdx.x * 16;
  const int t = threadIdx.x;
  const int wv = t >> 6, lane = t & 63, q = lane >> 4, c0 = lane & 15;
  const int cg = wv & 3, kc = wv >> 2;
  int rowm[4], colm[4];
  mfma_cdmap(lane, rowm, colm);

  __shared__ float pA[16][DOUT + 8];
  __shared__ float pB[16][DOUT + 8];

  floatx4 acc[4] = {};
  const float* hrow = h + (size_t)(i0 + c0) * DIN;     // A[m=c0][k]
  #pragma unroll
  for (int ktl = 0; ktl < 4; ++ktl) {
    const int kb = kc * 128 + ktl * 32 + q * 8;
    short8 af = pack8(hrow + kb);
    #pragma unroll
    for (int nt = 0; nt < 4; ++nt) {
      const int col = cg * 64 + nt * 16 + c0;          // B[k][n=c0]
      short8 bf = pack8(W + (size_t)col * DIN + kb);
      acc[nt] = __builtin_amdgcn_mfma_f32_16x16x32_bf16(af, bf, acc[nt], 0, 0, 0);
    }
  }

  auto writeT = [&](float (*P)[DOUT + 8]) {
    #pragma unroll
    for (int nt = 0; nt < 4; ++nt)
      #pragma unroll
      for (int r = 0; r < 4; ++r)
        P[rowm[r]][cg * 64 + nt * 16 + colm[r]] = acc[nt][r];
  };
  auto addB2A = [&]() {   // pA += pB, 16x256, 4 elems/thread
    const int row = t >> 6, c4 = (t & 63) * 4;
    float4* a = (float4*)&pA[row][c4];
    float4 bv = *(float4*)&pB[row][c4];
    float4 av = *a;
    av.x += bv.x; av.y += bv.y; av.z += bv.z; av.w += bv.w;
    *a = av;
  };

  if (kc == 0) writeT(pA);
  if (kc == 1) writeT(pB);
  __syncthreads();
  addB2A();
  __syncthreads();
  if (kc == 2) writeT(pB);
  __syncthreads();
  addB2A();
  __syncthreads();
  if (kc == 3) writeT(pB);
  __syncthreads();
  addB2A();
  __syncthreads();

  if (t < 64) {  // 16 rows x 4 heads -> s1, s2 (fp32)
    const int r = t & 15, hh = t >> 4;
    float s1 = 0.f, s2 = 0.f;
    for (int d = 0; d < HD; ++d) {
      float v = pA[r][hh * 64 + d];
      s1 += v * attn[hh * 128 + d];
      s2 += v * attn[hh * 128 + 64 + d];
    }
    s1g[hh * L_ + i0 + r] = s1;
    s2g[hh * L_ + i0 + r] = s2;
  }

  if (t < 256) {  // WhT store (d-major): thread t = column c, 16 bf16 along L
    const int c = t;
    union { unsigned u[4]; int4 v; } p0, p1;
    p0.u[0] = cvt2(pA[0][c],  pA[1][c]);  p0.u[1] = cvt2(pA[2][c],  pA[3][c]);
    p0.u[2] = cvt2(pA[4][c],  pA[5][c]);  p0.u[3] = cvt2(pA[6][c],  pA[7][c]);
    p1.u[0] = cvt2(pA[8][c],  pA[9][c]);  p1.u[1] = cvt2(pA[10][c], pA[11][c]);
    p1.u[2] = cvt2(pA[12][c], pA[13][c]); p1.u[3] = cvt2(pA[14][c], pA[15][c]);
    *(int4*)(WhT + (size_t)c * L_ + i0)     = p0.v;
    *(int4*)(WhT + (size_t)c * L_ + i0 + 8) = p1.v;
  }
}

// ---------------------------------------------------------------------------
// K2: masked softmax + PV + fused projection. Block 1024 = 16 waves:
// wave (hd = wv&3, jc = wv>>2 -> j-chunk jc*1024..+1023). Partial PV tiles
// (16x64 fp32) + partial denoms reduced via phased 2-plane LDS; Cn bf16;
// projection by waves 0-3.
// ---------------------------------------------------------------------------
__global__ __launch_bounds__(1024) void k2_attn(
    const int* __restrict__ A, const u16* __restrict__ WhT,
    const float* __restrict__ s1g, const float* __restrict__ s2g,
    const float* __restrict__ out_w, const float* __restrict__ out_b,
    float* __restrict__ out)
{
  const int i0 = blockIdx.x * 16;
  const int t = threadIdx.x;
  const int wv = t >> 6, lane = t & 63, q = lane >> 4, c0 = lane & 15;
  const int hd = wv & 3, jc = wv >> 2;
  int rowm[4], colm[4];
  mfma_cdmap(lane, rowm, colm);

  __shared__ float pA[NH][16][HD + 4];
  __shared__ float pB[NH][16][HD + 4];
  __shared__ float dden[NH][4][16];
  __shared__ float rcpS[NH][16];
  __shared__ u16  CnL[16][DOUT + 8];

  const float s1v = s1g[hd * L_ + i0 + c0];
  const int* Arow = A + (size_t)(i0 + c0) * L_;
  const float* s2h = s2g + (size_t)hd * L_;
  const u16* WhTh = WhT + (size_t)(hd * 64 + c0) * L_;

  floatx4 acc[4] = {};
  float dpart = 0.f;
  const int jbase = jc * 1024;
  #pragma unroll 2
  for (int kt = 0; kt < 32; ++kt) {
    const int kb = jbase + kt * 32 + q * 8;
    int4   m0 = *(const int4*)(Arow + kb);
    int4   m1 = *(const int4*)(Arow + kb + 4);
    float4 sa = *(const float4*)(s2h + kb);
    float4 sb = *(const float4*)(s2h + kb + 4);
    const int   mk[8] = {m0.x, m0.y, m0.z, m0.w, m1.x, m1.y, m1.z, m1.w};
    const float sv[8] = {sa.x, sa.y, sa.z, sa.w, sb.x, sb.y, sb.z, sb.w};
    float ex[8];
    #pragma unroll
    for (int jj = 0; jj < 8; ++jj) {
      float x = __expf(lrelu_clamp(s1v + sv[jj]));
      ex[jj] = (mk[jj] > 0) ? x : 0.f;                 // mask = (A > 0)
      dpart += ex[jj];
    }
    union { unsigned u[4]; short8 s; } pf;             // P A-frag [m=c0][k=j]
    pf.u[0] = cvt2(ex[0], ex[1]); pf.u[1] = cvt2(ex[2], ex[3]);
    pf.u[2] = cvt2(ex[4], ex[5]); pf.u[3] = cvt2(ex[6], ex[7]);
    #pragma unroll
    for (int nt = 0; nt < 4; ++nt) {
      short8 bfr = *(const short8*)(WhTh + (size_t)(nt * 16) * L_ + kb);
      acc[nt] = __builtin_amdgcn_mfma_f32_16x16x32_bf16(pf.s, bfr, acc[nt], 0, 0, 0);
    }
  }
  // partial denom of row c0 over this j-chunk
  dpart += __shfl_xor(dpart, 16, 64);
  dpart += __shfl_xor(dpart, 32, 64);
  if (lane < 16) dden[hd][jc][lane] = dpart;

  auto writeT = [&](float (*P)[HD + 4]) {
    #pragma unroll
    for (int nt = 0; nt < 4; ++nt)
      #pragma unroll
      for (int r = 0; r < 4; ++r)
        P[rowm[r]][nt * 16 + colm[r]] = acc[nt][r];
  };
  auto addB2A = [&]() {   // pA += pB, 4x16x64, 4 elems/thread
    const int h2 = t >> 8, rem = t & 255, row = rem >> 4, d4 = (rem & 15) * 4;
    float4* a = (float4*)&pA[h2][row][d4];
    float4 bv = *(float4*)&pB[h2][row][d4];
    float4 av = *a;
    av.x += bv.x; av.y += bv.y; av.z += bv.z; av.w += bv.w;
    *a = av;
  };

  if (jc == 0) writeT(pA[hd]);
  if (jc == 1) writeT(pB[hd]);
  __syncthreads();
  if (t < 64) {   // full-row reciprocal (dden complete at this barrier)
    const int hh = t >> 4, r = t & 15;
    float den = dden[hh][0][r] + dden[hh][1][r] + dden[hh][2][r] + dden[hh][3][r];
    rcpS[hh][r] = (den > 0.f) ? (1.f / den) : 0.f;     // empty row -> out = bias
  }
  addB2A();
  __syncthreads();
  if (jc == 2) writeT(pB[hd]);
  __syncthreads();
  addB2A();
  __syncthreads();
  if (jc == 3) writeT(pB[hd]);
  __syncthreads();
  addB2A();
  __syncthreads();

  {  // Cn (bf16): 16x256, 4 elems/thread
    const int row = t >> 6, c4 = (t & 63) * 4;
    #pragma unroll
    for (int x = 0; x < 4; ++x) {
      const int col = c4 + x;
      const int hh = col >> 6, d = col & 63;
      CnL[row][col] = f2bf(pA[hh][row][d] * rcpS[hh][row]);
    }
  }
  __syncthreads();

  if (wv < 4) {  // projection: Out2(16x256) = Cn @ out_w.T; wave cg -> 64 cols
    const int cg = wv;
    floatx4 o[4] = {};
    #pragma unroll
    for (int kt = 0; kt < DOUT / 32; ++kt) {
      const int kb = kt * 32 + q * 8;
      short8 afr = *(const short8*)(&CnL[c0][kb]);     // A[m=c0][k]
      #pragma unroll
      for (int nt = 0; nt < 4; ++nt) {
        const int col = cg * 64 + nt * 16 + c0;        // B[k][n=c0]
        short8 bfo = pack8(out_w + (size_t)col * DOUT + kb);
        o[nt] = __builtin_amdgcn_mfma_f32_16x16x32_bf16(afr, bfo, o[nt], 0, 0, 0);
      }
    }
    #pragma unroll
    for (int nt = 0; nt < 4; ++nt)
      #pragma unroll
      for (int r = 0; r < 4; ++r) {
        const int col = cg * 64 + nt * 16 + colm[r];
        out[(size_t)(i0 + rowm[r]) * DOUT + col] = o[nt][r] + out_b[col];
      }
  }
}

// ---------------------------------------------------------------------------
extern "C" void kernel_launch(void* const* d_in, const int* in_sizes, int n_in,
                              void* d_out, int out_size, void* d_ws, size_t ws_size,
                              hipStream_t stream) {
  const float* h     = (const float*)d_in[0];   // (4096, 512) fp32
  const int*   A     = (const int*)d_in[1];     // (4096, 4096) int32
  const float* W     = (const float*)d_in[2];   // (256, 512) fp32
  const float* attn  = (const float*)d_in[3];   // (4, 128) fp32
  const float* out_w = (const float*)d_in[4];   // (256, 256) fp32
  const float* out_b = (const float*)d_in[5];   // (256,) fp32
  float* outp = (float*)d_out;                  // (4096, 256) fp32

  // ws: WhT bf16 [256][4096] (2 MB) | s1 f32 [4][4096] | s2 f32 [4][4096]
  u16*   WhT = (u16*)d_ws;
  float* s1g = (float*)((char*)d_ws + (size_t)DOUT * L_ * 2);
  float* s2g = s1g + NH * L_;

  hipLaunchKernelGGL(k1_wh, dim3(L_ / 16), dim3(1024), 0, stream,
                     h, W, attn, WhT, s1g, s2g);
  hipLaunchKernelGGL(k2_attn, dim3(L_ / 16), dim3(1024), 0, stream,
                     A, WhT, s1g, s2g, out_w, out_b, outp);
}